// Round 2
// baseline (196.386 us; speedup 1.0000x reference)
//
#include <hip/hip_runtime.h>

#define BATCH 1024
#define IN_F 4096
#define OUT_F 4096
#define NCHUNK 8               // one batch-chunk per XCD (blockIdx % 8 ~ XCD)
#define CHUNK (BATCH / NCHUNK) // 128 batch elements per chunk -> 2MB xT slice/XCD

// ---------------- LDS-tiled transpose: dst[C][R] = src[R][C] ----------------
// grid: (C/32, R/32), block: (32, 8)
__global__ __launch_bounds__(256) void transpose_k(const float* __restrict__ src,
                                                   float* __restrict__ dst,
                                                   int R, int C) {
    __shared__ float tile[32][33];
    const int tx = threadIdx.x, ty = threadIdx.y;
    const int c0 = blockIdx.x * 32, r0 = blockIdx.y * 32;
#pragma unroll
    for (int j = 0; j < 4; ++j) {
        int r = r0 + ty + j * 8;
        tile[ty + j * 8][tx] = src[(size_t)r * C + c0 + tx];
    }
    __syncthreads();
#pragma unroll
    for (int j = 0; j < 4; ++j) {
        int c = c0 + ty + j * 8;
        dst[(size_t)c * R + r0 + tx] = tile[tx][ty + j * 8];
    }
}

// ---------------- CSC build: histogram -> scan -> scatter ----------------
__global__ void hist_k(const int* __restrict__ cols, int nnz, int* __restrict__ cnt) {
    int k = blockIdx.x * 256 + threadIdx.x;
    if (k < nnz) atomicAdd(&cnt[cols[k]], 1);
}

__global__ __launch_bounds__(1024) void scan_k(int* __restrict__ cnt_cursor,
                                               int* __restrict__ offs) {
    __shared__ int buf[2][1024];
    const int t = threadIdx.x;
    const int c0 = t * 4;
    int v0 = cnt_cursor[c0 + 0], v1 = cnt_cursor[c0 + 1];
    int v2 = cnt_cursor[c0 + 2], v3 = cnt_cursor[c0 + 3];
    int p = v0 + v1 + v2 + v3;
    buf[0][t] = p;
    __syncthreads();
    int s = 0;
    for (int off = 1; off < 1024; off <<= 1) {
        int d = s ^ 1;
        int x = buf[s][t];
        if (t >= off) x += buf[s][t - off];
        buf[d][t] = x;
        __syncthreads();
        s = d;
    }
    int incl = buf[s][t];
    int base = incl - p;
    offs[c0 + 0] = base;
    offs[c0 + 1] = base + v0;
    offs[c0 + 2] = base + v0 + v1;
    offs[c0 + 3] = base + v0 + v1 + v2;
    cnt_cursor[c0 + 0] = base;
    cnt_cursor[c0 + 1] = base + v0;
    cnt_cursor[c0 + 2] = base + v0 + v1;
    cnt_cursor[c0 + 3] = base + v0 + v1 + v2;
    if (t == 1023) offs[OUT_F] = incl;
}

// pack (row, valbits) into int2 -> one 8B load per entry in the hot loop
__global__ void scatter_k(const int* __restrict__ rows, const int* __restrict__ cols,
                          const float* __restrict__ vals, int nnz,
                          int* __restrict__ cursor, int2* __restrict__ rv) {
    int k = blockIdx.x * 256 + threadIdx.x;
    if (k < nnz) {
        int c = cols[k];
        int pos = atomicAdd(&cursor[c], 1);
        rv[pos] = make_int2(rows[k], __float_as_int(vals[k]));
    }
}

// ---------------- main: chunked, XCD-affine, no atomics ----------------
// grid: (OUT_F/4) * NCHUNK blocks; chunk = blockIdx%8 pins the 2MB xT slice
// to one XCD's L2. Block = 4 waves; wave w owns column colBase+w; 64 lanes
// cover the 128-batch chunk as float2.
__global__ __launch_bounds__(256) void spmm_k(const float* __restrict__ xT,
                                              const int* __restrict__ offs,
                                              const int2* __restrict__ rv,
                                              const float* __restrict__ bias,
                                              float* __restrict__ outT) {
    const int chunk = blockIdx.x & (NCHUNK - 1);
    const int colBase = (blockIdx.x >> 3) * 4;
    const int w = threadIdx.x >> 6;
    const int lane = threadIdx.x & 63;
    const int c = colBase + w;
    const int boff = (chunk * CHUNK) / 2 + lane;  // float2 index into a row

    int e = offs[c];
    const int end = offs[c + 1];
    const float bb = bias[c];
    float2 acc = make_float2(bb, bb);
    const float2* __restrict__ x2 = (const float2*)xT;

    for (; e + 1 < end; e += 2) {
        int2 e0 = rv[e];
        int2 e1 = rv[e + 1];
        float2 xa = x2[(size_t)e0.x * (BATCH / 2) + boff];
        float2 xb = x2[(size_t)e1.x * (BATCH / 2) + boff];
        float va = __int_as_float(e0.y);
        float vb = __int_as_float(e1.y);
        acc.x = fmaf(va, xa.x, acc.x);
        acc.y = fmaf(va, xa.y, acc.y);
        acc.x = fmaf(vb, xb.x, acc.x);
        acc.y = fmaf(vb, xb.y, acc.y);
    }
    if (e < end) {
        int2 e0 = rv[e];
        float2 xa = x2[(size_t)e0.x * (BATCH / 2) + boff];
        float va = __int_as_float(e0.y);
        acc.x = fmaf(va, xa.x, acc.x);
        acc.y = fmaf(va, xa.y, acc.y);
    }
    ((float2*)outT)[(size_t)c * (BATCH / 2) + boff] = acc;
}

// ---------------- fallback (insufficient ws): atomic scatter ----------------
__global__ void bias_init_k(const float* __restrict__ bias, float* __restrict__ out) {
    int i = blockIdx.x * 256 + threadIdx.x;
    out[i] = bias[i & (OUT_F - 1)];
}
__global__ void fallback_k(const float* __restrict__ x, const float* __restrict__ vals,
                           const int* __restrict__ rows, const int* __restrict__ cols,
                           float* __restrict__ out) {
    int k = blockIdx.x;
    int r = rows[k], c = cols[k];
    float v = vals[k];
    for (int b = threadIdx.x; b < BATCH; b += 256)
        atomicAdd(&out[(size_t)b * OUT_F + c], v * x[(size_t)b * IN_F + r]);
}

extern "C" void kernel_launch(void* const* d_in, const int* in_sizes, int n_in,
                              void* d_out, int out_size, void* d_ws, size_t ws_size,
                              hipStream_t stream) {
    const float* x    = (const float*)d_in[0];
    const float* vals = (const float*)d_in[1];
    const float* bias = (const float*)d_in[2];
    const int*   rows = (const int*)d_in[3];
    const int*   cols = (const int*)d_in[4];
    float* out = (float*)d_out;
    const int nnz = in_sizes[1];

    size_t off = 0;
    auto alloc = [&](size_t bytes) {
        void* p = (char*)d_ws + off;
        off += (bytes + 255) & ~(size_t)255;
        return p;
    };
    float* xT     = (float*)alloc((size_t)IN_F * BATCH * 4);
    float* outT   = (float*)alloc((size_t)OUT_F * BATCH * 4);
    int*   offs   = (int*)alloc((OUT_F + 1) * 4);
    int*   cursor = (int*)alloc(OUT_F * 4);
    int2*  rv     = (int2*)alloc((size_t)nnz * 8);

    if (off > ws_size) {
        bias_init_k<<<(BATCH * OUT_F) / 256, 256, 0, stream>>>(bias, out);
        fallback_k<<<nnz, 256, 0, stream>>>(x, vals, rows, cols, out);
        return;
    }

    hipMemsetAsync(cursor, 0, OUT_F * 4, stream);
    transpose_k<<<dim3(IN_F / 32, BATCH / 32), dim3(32, 8), 0, stream>>>(x, xT, BATCH, IN_F);
    hist_k<<<(nnz + 255) / 256, 256, 0, stream>>>(cols, nnz, cursor);
    scan_k<<<1, 1024, 0, stream>>>(cursor, offs);
    scatter_k<<<(nnz + 255) / 256, 256, 0, stream>>>(rows, cols, vals, nnz, cursor, rv);
    spmm_k<<<(OUT_F / 4) * NCHUNK, 256, 0, stream>>>(xT, offs, rv, bias, outT);
    transpose_k<<<dim3(BATCH / 32, OUT_F / 32), dim3(32, 8), 0, stream>>>(outT, out, OUT_F, BATCH);
}

// Round 3
// 164.988 us; speedup vs baseline: 1.1903x; 1.1903x over previous
//
#include <hip/hip_runtime.h>

#define BATCH 1024
#define IN_F 4096
#define OUT_F 4096
#define NCHUNK 8                // one batch-chunk per XCD (blockIdx % 8 ~ XCD)
#define CHUNK (BATCH / NCHUNK)  // 128 batch elems/chunk -> 2MB xT slice per XCD L2
#define GRP 8                   // entries per software-pipelined group

// ---------------- LDS-tiled transpose: dst[C][R] = src[R][C] ----------------
__global__ __launch_bounds__(256) void transpose_k(const float* __restrict__ src,
                                                   float* __restrict__ dst,
                                                   int R, int C) {
    __shared__ float tile[32][33];
    const int tx = threadIdx.x, ty = threadIdx.y;
    const int c0 = blockIdx.x * 32, r0 = blockIdx.y * 32;
#pragma unroll
    for (int j = 0; j < 4; ++j) {
        int r = r0 + ty + j * 8;
        tile[ty + j * 8][tx] = src[(size_t)r * C + c0 + tx];
    }
    __syncthreads();
#pragma unroll
    for (int j = 0; j < 4; ++j) {
        int c = c0 + ty + j * 8;
        dst[(size_t)c * R + r0 + tx] = tile[tx][ty + j * 8];
    }
}

// ---------------- CSC build: histogram -> padded scan -> scatter ----------------
__global__ void hist_k(const int* __restrict__ cols, int nnz, int* __restrict__ cnt) {
    int k = blockIdx.x * 256 + threadIdx.x;
    if (k < nnz) atomicAdd(&cnt[cols[k]], 1);
}

// single block, 1024 threads, 4 bins/thread; counts padded up to multiple of GRP
// so every column segment is GRP-aligned (64B) and a whole number of groups.
__global__ __launch_bounds__(1024) void scan_k(int* __restrict__ cnt_cursor,
                                               int* __restrict__ offs) {
    __shared__ int buf[2][1024];
    const int t = threadIdx.x;
    const int c0 = t * 4;
    int v0 = cnt_cursor[c0 + 0], v1 = cnt_cursor[c0 + 1];
    int v2 = cnt_cursor[c0 + 2], v3 = cnt_cursor[c0 + 3];
    int q0 = (v0 + GRP - 1) & ~(GRP - 1);
    int q1 = (v1 + GRP - 1) & ~(GRP - 1);
    int q2 = (v2 + GRP - 1) & ~(GRP - 1);
    int q3 = (v3 + GRP - 1) & ~(GRP - 1);
    int p = q0 + q1 + q2 + q3;
    buf[0][t] = p;
    __syncthreads();
    int s = 0;
    for (int off = 1; off < 1024; off <<= 1) {
        int d = s ^ 1;
        int x = buf[s][t];
        if (t >= off) x += buf[s][t - off];
        buf[d][t] = x;
        __syncthreads();
        s = d;
    }
    int incl = buf[s][t];
    int base = incl - p;
    offs[c0 + 0] = base;
    offs[c0 + 1] = base + q0;
    offs[c0 + 2] = base + q0 + q1;
    offs[c0 + 3] = base + q0 + q1 + q2;
    cnt_cursor[c0 + 0] = base;
    cnt_cursor[c0 + 1] = base + q0;
    cnt_cursor[c0 + 2] = base + q0 + q1;
    cnt_cursor[c0 + 3] = base + q0 + q1 + q2;
    if (t == 1023) offs[OUT_F] = incl;
}

// rv pre-zeroed (memset) -> pad slots stay (row=0, val=0.0f): harmless FMA of 0
__global__ void scatter_k(const int* __restrict__ rows, const int* __restrict__ cols,
                          const float* __restrict__ vals, int nnz,
                          int* __restrict__ cursor, int2* __restrict__ rv) {
    int k = blockIdx.x * 256 + threadIdx.x;
    if (k < nnz) {
        int c = cols[k];
        int pos = atomicAdd(&cursor[c], 1);
        rv[pos] = make_int2(rows[k], __float_as_int(vals[k]));
    }
}

// ---------------- main: chunked + XCD-affine + software-pipelined ----------------
// grid (OUT_F/4)*NCHUNK, 4 waves/block; wave w owns column colBase+w (scalar via
// readfirstlane); lanes cover 128-batch chunk as float2. Inner loop: prefetch
// next 8-entry rv group (4x int4) while 8 independent x-loads are in flight.
__global__ __launch_bounds__(256) void spmm_k(const float* __restrict__ xT,
                                              const int* __restrict__ offs,
                                              const int2* __restrict__ rv,
                                              const float* __restrict__ bias,
                                              float* __restrict__ outT) {
    const int chunk = blockIdx.x & (NCHUNK - 1);
    const int colBase = (blockIdx.x >> 3) * 4;
    const int w = threadIdx.x >> 6;
    const int lane = threadIdx.x & 63;
    const int c = __builtin_amdgcn_readfirstlane(colBase + w);  // wave-uniform
    const int boff = (chunk * CHUNK) / 2 + lane;                // float2 idx in row

    const int start = offs[c];
    const int end = offs[c + 1];          // (end-start) % GRP == 0
    const int groups = (end - start) >> 3;

    const float bb = bias[c];
    float2 acc = make_float2(bb, bb);
    const float2* __restrict__ xb = (const float2*)xT;
    const int4* __restrict__ p = (const int4*)(rv + start);  // 64B aligned

    // prefetch group 0 (slack entries at end of rv make this safe even if groups==0)
    int4 r0 = p[0], r1 = p[1], r2 = p[2], r3 = p[3];
    for (int g = 0; g < groups; ++g) {
        const int4* pn = p + (size_t)(g + 1) * 4;
        int4 n0 = pn[0], n1 = pn[1], n2 = pn[2], n3 = pn[3];  // next group (slack-safe)
        // 8 independent x-loads: 4KB in flight per wave
        float2 y0 = xb[(size_t)r0.x * (BATCH / 2) + boff];
        float2 y1 = xb[(size_t)r0.z * (BATCH / 2) + boff];
        float2 y2 = xb[(size_t)r1.x * (BATCH / 2) + boff];
        float2 y3 = xb[(size_t)r1.z * (BATCH / 2) + boff];
        float2 y4 = xb[(size_t)r2.x * (BATCH / 2) + boff];
        float2 y5 = xb[(size_t)r2.z * (BATCH / 2) + boff];
        float2 y6 = xb[(size_t)r3.x * (BATCH / 2) + boff];
        float2 y7 = xb[(size_t)r3.z * (BATCH / 2) + boff];
        float v0 = __int_as_float(r0.y), v1 = __int_as_float(r0.w);
        float v2 = __int_as_float(r1.y), v3 = __int_as_float(r1.w);
        float v4 = __int_as_float(r2.y), v5 = __int_as_float(r2.w);
        float v6 = __int_as_float(r3.y), v7 = __int_as_float(r3.w);
        acc.x = fmaf(v0, y0.x, acc.x); acc.y = fmaf(v0, y0.y, acc.y);
        acc.x = fmaf(v1, y1.x, acc.x); acc.y = fmaf(v1, y1.y, acc.y);
        acc.x = fmaf(v2, y2.x, acc.x); acc.y = fmaf(v2, y2.y, acc.y);
        acc.x = fmaf(v3, y3.x, acc.x); acc.y = fmaf(v3, y3.y, acc.y);
        acc.x = fmaf(v4, y4.x, acc.x); acc.y = fmaf(v4, y4.y, acc.y);
        acc.x = fmaf(v5, y5.x, acc.x); acc.y = fmaf(v5, y5.y, acc.y);
        acc.x = fmaf(v6, y6.x, acc.x); acc.y = fmaf(v6, y6.y, acc.y);
        acc.x = fmaf(v7, y7.x, acc.x); acc.y = fmaf(v7, y7.y, acc.y);
        r0 = n0; r1 = n1; r2 = n2; r3 = n3;
    }
    ((float2*)outT)[(size_t)c * (BATCH / 2) + boff] = acc;
}

// ---------------- fallback (insufficient ws): atomic scatter ----------------
__global__ void bias_init_k(const float* __restrict__ bias, float* __restrict__ out) {
    int i = blockIdx.x * 256 + threadIdx.x;
    out[i] = bias[i & (OUT_F - 1)];
}
__global__ void fallback_k(const float* __restrict__ x, const float* __restrict__ vals,
                           const int* __restrict__ rows, const int* __restrict__ cols,
                           float* __restrict__ out) {
    int k = blockIdx.x;
    int r = rows[k], c = cols[k];
    float v = vals[k];
    for (int b = threadIdx.x; b < BATCH; b += 256)
        atomicAdd(&out[(size_t)b * OUT_F + c], v * x[(size_t)b * IN_F + r]);
}

extern "C" void kernel_launch(void* const* d_in, const int* in_sizes, int n_in,
                              void* d_out, int out_size, void* d_ws, size_t ws_size,
                              hipStream_t stream) {
    const float* x    = (const float*)d_in[0];
    const float* vals = (const float*)d_in[1];
    const float* bias = (const float*)d_in[2];
    const int*   rows = (const int*)d_in[3];
    const int*   cols = (const int*)d_in[4];
    float* out = (float*)d_out;
    const int nnz = in_sizes[1];

    // worst-case padded entries + GRP slack for the unconditional prefetch
    const size_t rv_cap = (size_t)nnz + (size_t)(GRP - 1) * OUT_F + GRP;

    size_t off = 0;
    auto alloc = [&](size_t bytes) {
        void* p = (char*)d_ws + off;
        off += (bytes + 255) & ~(size_t)255;
        return p;
    };
    float* xT     = (float*)alloc((size_t)IN_F * BATCH * 4);
    float* outT   = (float*)alloc((size_t)OUT_F * BATCH * 4);
    int*   offs   = (int*)alloc((OUT_F + 1) * 4);
    int*   cursor = (int*)alloc(OUT_F * 4);
    int2*  rv     = (int2*)alloc(rv_cap * 8);

    if (off > ws_size) {
        bias_init_k<<<(BATCH * OUT_F) / 256, 256, 0, stream>>>(bias, out);
        fallback_k<<<nnz, 256, 0, stream>>>(x, vals, rows, cols, out);
        return;
    }

    hipMemsetAsync(cursor, 0, OUT_F * 4, stream);
    hipMemsetAsync(rv, 0, rv_cap * 8, stream);  // pads become (row=0, val=0)
    transpose_k<<<dim3(IN_F / 32, BATCH / 32), dim3(32, 8), 0, stream>>>(x, xT, BATCH, IN_F);
    hist_k<<<(nnz + 255) / 256, 256, 0, stream>>>(cols, nnz, cursor);
    scan_k<<<1, 1024, 0, stream>>>(cursor, offs);
    scatter_k<<<(nnz + 255) / 256, 256, 0, stream>>>(rows, cols, vals, nnz, cursor, rv);
    spmm_k<<<(OUT_F / 4) * NCHUNK, 256, 0, stream>>>(xT, offs, rv, bias, outT);
    transpose_k<<<dim3(BATCH / 32, OUT_F / 32), dim3(32, 8), 0, stream>>>(outT, out, OUT_F, BATCH);
}

// Round 4
// 149.256 us; speedup vs baseline: 1.3158x; 1.1054x over previous
//
#include <hip/hip_runtime.h>

#define BATCH 1024
#define IN_F 4096
#define OUT_F 4096
#define NCHUNK 8                // one batch-chunk per XCD (blockIdx % 8 ~ XCD)
#define CHUNK (BATCH / NCHUNK)  // 128 batch elems/chunk -> 2MB xT slice per XCD L2
#define GRP 8                   // entries per software-pipelined group

// ------------- transpose x (dst[C][R] = src[R][C]) + zero cursor/rv -------------
// grid: (C/32, R/32), block: (32,8). Also grid-stride zeroes cursor + rv so the
// two hipMemsetAsync graph nodes disappear (hist/scatter run in later dispatches).
__global__ __launch_bounds__(256) void transpose_zero_k(const float* __restrict__ src,
                                                        float* __restrict__ dst,
                                                        int R, int C,
                                                        int* __restrict__ cursor,
                                                        int4* __restrict__ rvz,
                                                        int rvz_n) {
    __shared__ float tile[32][33];
    const int tx = threadIdx.x, ty = threadIdx.y;
    const int c0 = blockIdx.x * 32, r0 = blockIdx.y * 32;
#pragma unroll
    for (int j = 0; j < 4; ++j) {
        int r = r0 + ty + j * 8;
        tile[ty + j * 8][tx] = src[(size_t)r * C + c0 + tx];
    }
    // zeroing work (independent of the tile)
    const int tid = ty * 32 + tx;
    const int gtid = (blockIdx.y * gridDim.x + blockIdx.x) * 256 + tid;
    const int nthreads = gridDim.x * gridDim.y * 256;
    if (gtid < OUT_F) cursor[gtid] = 0;
    for (int i = gtid; i < rvz_n; i += nthreads) rvz[i] = make_int4(0, 0, 0, 0);
    __syncthreads();
#pragma unroll
    for (int j = 0; j < 4; ++j) {
        int c = c0 + ty + j * 8;
        dst[(size_t)c * R + r0 + tx] = tile[tx][ty + j * 8];
    }
}

// ---------------- CSC build: histogram -> padded scan -> scatter ----------------
__global__ void hist_k(const int* __restrict__ cols, int nnz, int* __restrict__ cnt) {
    int k = blockIdx.x * 256 + threadIdx.x;
    if (k < nnz) atomicAdd(&cnt[cols[k]], 1);
}

// single block, 1024 threads, 4 bins/thread; counts padded to multiple of GRP so
// every column segment is GRP-aligned (64B) and a whole number of groups.
__global__ __launch_bounds__(1024) void scan_k(int* __restrict__ cnt_cursor,
                                               int* __restrict__ offs) {
    __shared__ int buf[2][1024];
    const int t = threadIdx.x;
    const int c0 = t * 4;
    int v0 = cnt_cursor[c0 + 0], v1 = cnt_cursor[c0 + 1];
    int v2 = cnt_cursor[c0 + 2], v3 = cnt_cursor[c0 + 3];
    int q0 = (v0 + GRP - 1) & ~(GRP - 1);
    int q1 = (v1 + GRP - 1) & ~(GRP - 1);
    int q2 = (v2 + GRP - 1) & ~(GRP - 1);
    int q3 = (v3 + GRP - 1) & ~(GRP - 1);
    int p = q0 + q1 + q2 + q3;
    buf[0][t] = p;
    __syncthreads();
    int s = 0;
    for (int off = 1; off < 1024; off <<= 1) {
        int d = s ^ 1;
        int x = buf[s][t];
        if (t >= off) x += buf[s][t - off];
        buf[d][t] = x;
        __syncthreads();
        s = d;
    }
    int incl = buf[s][t];
    int base = incl - p;
    offs[c0 + 0] = base;
    offs[c0 + 1] = base + q0;
    offs[c0 + 2] = base + q0 + q1;
    offs[c0 + 3] = base + q0 + q1 + q2;
    cnt_cursor[c0 + 0] = base;
    cnt_cursor[c0 + 1] = base + q0;
    cnt_cursor[c0 + 2] = base + q0 + q1;
    cnt_cursor[c0 + 3] = base + q0 + q1 + q2;
    if (t == 1023) offs[OUT_F] = incl;
}

// rv pre-zeroed -> pad slots stay (row=0, val=0.0f): harmless FMA of 0
__global__ void scatter_k(const int* __restrict__ rows, const int* __restrict__ cols,
                          const float* __restrict__ vals, int nnz,
                          int* __restrict__ cursor, int2* __restrict__ rv) {
    int k = blockIdx.x * 256 + threadIdx.x;
    if (k < nnz) {
        int c = cols[k];
        int pos = atomicAdd(&cursor[c], 1);
        rv[pos] = make_int2(rows[k], __float_as_int(vals[k]));
    }
}

// ---------------- main: half-wave float4 + direct [b][c] store ----------------
// grid (OUT_F/4)*NCHUNK, 4 waves/block; wave w owns column colBase+w. Lanes 0-31
// process even entries, lanes 32-63 odd entries, each half covering the 128-batch
// chunk as float4 (32 lanes x 16B = 512B -> dwordx4, 1KB per wave instruction).
// Halves are summed via shfl at the end; lanes 0-31 store 4 strided dwords
// straight into out[b][c] (same-XCD L2 merges column-adjacent blocks into full
// 64B lines), eliminating outT and the second transpose kernel.
// __launch_bounds__(256,4): VGPR budget ~128 so the 4 dwordx4 loads stay
// clustered/in-flight instead of being re-serialized for occupancy (R3: VGPR=20).
__global__ __launch_bounds__(256, 4) void spmm_k(const float* __restrict__ xT,
                                                 const int* __restrict__ offs,
                                                 const int2* __restrict__ rv,
                                                 const float* __restrict__ bias,
                                                 float* __restrict__ out) {
    const int chunk = blockIdx.x & (NCHUNK - 1);
    const int colBase = (blockIdx.x >> 3) * 4;
    const int w = threadIdx.x >> 6;
    const int lane = threadIdx.x & 63;
    const int half = lane >> 5;  // 0: even entries, 1: odd entries
    const int hl = lane & 31;    // lane within half
    const int c = __builtin_amdgcn_readfirstlane(colBase + w);  // wave-uniform

    const int start = offs[c];
    const int groups = (offs[c + 1] - start) >> 3;  // segment padded to 8 entries

    const float4* __restrict__ xb4 = (const float4*)xT;  // row stride = 256 float4
    const int boff = chunk * (CHUNK / 4) + hl;           // float4 idx within row
    const int4* __restrict__ p = (const int4*)(rv + start);  // 64B aligned, uniform

    float4 acc;
    const float bb = half ? 0.0f : bias[c];  // bias once (halves are summed later)
    acc.x = bb; acc.y = bb; acc.z = bb; acc.w = bb;

    // prefetch group 0 (zeroed slack at end of rv makes this safe if groups==0)
    int4 r0 = p[0], r1 = p[1], r2 = p[2], r3 = p[3];
    for (int g = 0; g < groups; ++g) {
        const int4* pn = p + (size_t)(g + 1) * 4;
        int4 n0 = pn[0], n1 = pn[1], n2 = pn[2], n3 = pn[3];
        // entry select per half: (xy)=even entry, (zw)=odd entry of each pair
        int row0 = half ? r0.z : r0.x;
        int row1 = half ? r1.z : r1.x;
        int row2 = half ? r2.z : r2.x;
        int row3 = half ? r3.z : r3.x;
        float v0 = __int_as_float(half ? r0.w : r0.y);
        float v1 = __int_as_float(half ? r1.w : r1.y);
        float v2 = __int_as_float(half ? r2.w : r2.y);
        float v3 = __int_as_float(half ? r3.w : r3.y);
        // 4 independent 1KB wave-loads in flight
        float4 y0 = xb4[(size_t)row0 * (BATCH / 4) + boff];
        float4 y1 = xb4[(size_t)row1 * (BATCH / 4) + boff];
        float4 y2 = xb4[(size_t)row2 * (BATCH / 4) + boff];
        float4 y3 = xb4[(size_t)row3 * (BATCH / 4) + boff];
        acc.x = fmaf(v0, y0.x, acc.x); acc.y = fmaf(v0, y0.y, acc.y);
        acc.z = fmaf(v0, y0.z, acc.z); acc.w = fmaf(v0, y0.w, acc.w);
        acc.x = fmaf(v1, y1.x, acc.x); acc.y = fmaf(v1, y1.y, acc.y);
        acc.z = fmaf(v1, y1.z, acc.z); acc.w = fmaf(v1, y1.w, acc.w);
        acc.x = fmaf(v2, y2.x, acc.x); acc.y = fmaf(v2, y2.y, acc.y);
        acc.z = fmaf(v2, y2.z, acc.z); acc.w = fmaf(v2, y2.w, acc.w);
        acc.x = fmaf(v3, y3.x, acc.x); acc.y = fmaf(v3, y3.y, acc.y);
        acc.z = fmaf(v3, y3.z, acc.z); acc.w = fmaf(v3, y3.w, acc.w);
        r0 = n0; r1 = n1; r2 = n2; r3 = n3;
    }

    // combine halves: lane l (<32) += lane l+32
    acc.x += __shfl_down(acc.x, 32);
    acc.y += __shfl_down(acc.y, 32);
    acc.z += __shfl_down(acc.z, 32);
    acc.w += __shfl_down(acc.w, 32);

    if (half == 0) {
        const int b0 = chunk * CHUNK + hl * 4;
        float* op = out + (size_t)b0 * OUT_F + c;
        op[0 * OUT_F] = acc.x;
        op[1 * OUT_F] = acc.y;
        op[2 * OUT_F] = acc.z;
        op[3 * OUT_F] = acc.w;
    }
}

// ---------------- fallback (insufficient ws): atomic scatter ----------------
__global__ void bias_init_k(const float* __restrict__ bias, float* __restrict__ out) {
    int i = blockIdx.x * 256 + threadIdx.x;
    out[i] = bias[i & (OUT_F - 1)];
}
__global__ void fallback_k(const float* __restrict__ x, const float* __restrict__ vals,
                           const int* __restrict__ rows, const int* __restrict__ cols,
                           float* __restrict__ out) {
    int k = blockIdx.x;
    int r = rows[k], c = cols[k];
    float v = vals[k];
    for (int b = threadIdx.x; b < BATCH; b += 256)
        atomicAdd(&out[(size_t)b * OUT_F + c], v * x[(size_t)b * IN_F + r]);
}

extern "C" void kernel_launch(void* const* d_in, const int* in_sizes, int n_in,
                              void* d_out, int out_size, void* d_ws, size_t ws_size,
                              hipStream_t stream) {
    const float* x    = (const float*)d_in[0];
    const float* vals = (const float*)d_in[1];
    const float* bias = (const float*)d_in[2];
    const int*   rows = (const int*)d_in[3];
    const int*   cols = (const int*)d_in[4];
    float* out = (float*)d_out;
    const int nnz = in_sizes[1];

    // worst-case padded entries + GRP slack for the unconditional prefetch
    const size_t rv_cap = (size_t)nnz + (size_t)(GRP - 1) * OUT_F + GRP;
    const int rvz_n = (int)((rv_cap * 8 + 15) / 16);  // int4 count to zero

    size_t off = 0;
    auto alloc = [&](size_t bytes) {
        void* p = (char*)d_ws + off;
        off += (bytes + 255) & ~(size_t)255;
        return p;
    };
    float* xT     = (float*)alloc((size_t)IN_F * BATCH * 4);
    int*   offs   = (int*)alloc((OUT_F + 1) * 4);
    int*   cursor = (int*)alloc(OUT_F * 4);
    int2*  rv     = (int2*)alloc(rv_cap * 8 + 16);

    if (off > ws_size) {
        bias_init_k<<<(BATCH * OUT_F) / 256, 256, 0, stream>>>(bias, out);
        fallback_k<<<nnz, 256, 0, stream>>>(x, vals, rows, cols, out);
        return;
    }

    transpose_zero_k<<<dim3(IN_F / 32, BATCH / 32), dim3(32, 8), 0, stream>>>(
        x, xT, BATCH, IN_F, cursor, (int4*)rv, rvz_n);
    hist_k<<<(nnz + 255) / 256, 256, 0, stream>>>(cols, nnz, cursor);
    scan_k<<<1, 1024, 0, stream>>>(cursor, offs);
    scatter_k<<<(nnz + 255) / 256, 256, 0, stream>>>(rows, cols, vals, nnz, cursor, rv);
    spmm_k<<<(OUT_F / 4) * NCHUNK, 256, 0, stream>>>(xT, offs, rv, bias, out);
}